// Round 1
// baseline (4994.800 us; speedup 1.0000x reference)
//
#include <hip/hip_runtime.h>
#include <math.h>

#define B_ 16
#define T_ 512
#define FEAT_ 40
#define DM 256
#define DI 512
#define DS_ 16
#define NL 8
#define NC 35
#define NTOK (B_*T_)

__device__ __forceinline__ float sigmoidf_(float x){ return 1.f/(1.f+__expf(-x)); }
__device__ __forceinline__ float siluf_(float x){ return x*sigmoidf_(x); }

// block-wide (256 threads) sum; red must have 8 floats; slot = 0 or 1
__device__ __forceinline__ float blocksum256(float v, float* red, int slot) {
  #pragma unroll
  for (int off = 32; off > 0; off >>= 1) v += __shfl_down(v, off, 64);
  int lane = threadIdx.x & 63, wid = threadIdx.x >> 6;
  if (lane == 0) red[slot*4 + wid] = v;
  __syncthreads();
  return red[slot*4+0]+red[slot*4+1]+red[slot*4+2]+red[slot*4+3];
}

// ---------------- input projection + LN + silu ----------------
// one block per token, 256 threads (one per channel)
__global__ __launch_bounds__(256) void k_proj_ln(
    const float* __restrict__ x, const float* __restrict__ pw,
    const float* __restrict__ pb, const float* __restrict__ g,
    const float* __restrict__ be, float* __restrict__ h) {
  __shared__ float xs[FEAT_];
  __shared__ float red[8];
  int tok = blockIdx.x;
  int j = threadIdx.x;
  if (j < FEAT_) xs[j] = x[tok*FEAT_ + j];
  __syncthreads();
  float acc = pb[j];
  #pragma unroll
  for (int k = 0; k < FEAT_; k++) acc += xs[k] * pw[j*FEAT_ + k];
  float m = blocksum256(acc, red, 0) * (1.f/DM);
  float d = acc - m;
  float var = blocksum256(d*d, red, 1) * (1.f/DM);
  float v = d * rsqrtf(var + 1e-5f) * g[j] + be[j];
  h[tok*DM + j] = siluf_(v);
}

// ---------------- layernorm over DM ----------------
__global__ __launch_bounds__(256) void k_ln(
    const float* __restrict__ in, const float* __restrict__ g,
    const float* __restrict__ be, float* __restrict__ outp) {
  __shared__ float red[8];
  int tok = blockIdx.x;
  int j = threadIdx.x;
  float v = in[tok*DM + j];
  float m = blocksum256(v, red, 0) * (1.f/DM);
  float d = v - m;
  float var = blocksum256(d*d, red, 1) * (1.f/DM);
  outp[tok*DM + j] = d * rsqrtf(var + 1e-5f) * g[j] + be[j];
}

// ---------------- generic tiled f32 GEMM: C = act(A @ W^T + bias) ----------------
// A: M x K with row stride lda; W: N x K row-major; C: M x N
// ACT: 0 none, 1 softplus.  RESID: 1 -> C += result
template<int ACT, int RESID>
__global__ __launch_bounds__(256) void k_gemm(
    const float* __restrict__ A, const float* __restrict__ W,
    const float* __restrict__ bias, float* __restrict__ C,
    int M, int N, int K, int lda) {
  __shared__ __align__(16) float As[16][68];
  __shared__ __align__(16) float Ws[16][68];
  int tid = threadIdx.x;
  int tx = tid & 15, ty = tid >> 4;
  int m0 = blockIdx.x * 64, n0 = blockIdx.y * 64;
  int lk = tid & 15;   // k within tile
  int lr = tid >> 4;   // row base
  float acc[4][4] = {};
  for (int k0 = 0; k0 < K; k0 += 16) {
    #pragma unroll
    for (int i = 0; i < 4; i++) {
      int m = m0 + lr + i*16;
      As[lk][lr + i*16] = A[(size_t)m*lda + k0 + lk];
    }
    #pragma unroll
    for (int i = 0; i < 4; i++) {
      int n = n0 + lr + i*16;
      Ws[lk][lr + i*16] = (n < N) ? W[(size_t)n*K + k0 + lk] : 0.f;
    }
    __syncthreads();
    #pragma unroll
    for (int kk = 0; kk < 16; kk++) {
      float a[4], b[4];
      #pragma unroll
      for (int i = 0; i < 4; i++) a[i] = As[kk][ty*4 + i];
      #pragma unroll
      for (int j = 0; j < 4; j++) b[j] = Ws[kk][tx*4 + j];
      #pragma unroll
      for (int i = 0; i < 4; i++)
        #pragma unroll
        for (int j = 0; j < 4; j++)
          acc[i][j] += a[i] * b[j];
    }
    __syncthreads();
  }
  #pragma unroll
  for (int i = 0; i < 4; i++) {
    int m = m0 + ty*4 + i;
    #pragma unroll
    for (int j = 0; j < 4; j++) {
      int n = n0 + tx*4 + j;
      if (n < N) {
        float v = acc[i][j];
        if (bias) v += bias[n];
        if (ACT == 1) v = (v > 20.f) ? v : log1pf(__expf(v));
        if (RESID) C[(size_t)m*N + n] += v;
        else       C[(size_t)m*N + n] = v;
      }
    }
  }
}

// ---------------- depthwise causal conv (k=4) + silu ----------------
// input = first DI channels of xz rows (row width 1024)
__global__ __launch_bounds__(256) void k_conv_silu(
    const float* __restrict__ xz, const float* __restrict__ w,
    const float* __restrict__ bias, float* __restrict__ u) {
  int idx = blockIdx.x * 256 + threadIdx.x;   // b*T*DI
  int d = idx & (DI-1);
  int t = (idx >> 9) & (T_-1);
  int b = idx >> 18;
  const float* base = xz + (size_t)b * T_ * 1024;
  float acc = bias[d];
  #pragma unroll
  for (int j = 0; j < 4; j++) {
    int tt = t - 3 + j;
    if (tt >= 0) acc += w[d*4 + j] * base[(size_t)tt*1024 + d];
  }
  u[idx] = siluf_(acc);
}

// ---------------- selective scan (+ u*Dp, * silu(z)) ----------------
// 16 lanes per (b,d) pair; lane = state index s. Writes g in-place over dt buf.
__global__ __launch_bounds__(256) void k_scan(
    const float* __restrict__ dt, const float* __restrict__ u,
    const float* __restrict__ dbl, const float* __restrict__ xz,
    const float* __restrict__ A_log, const float* __restrict__ Dp,
    float* __restrict__ g_out) {
  int tid = threadIdx.x;
  int s = tid & 15;
  int grp = tid >> 4;                 // 0..15
  int p = blockIdx.x * 16 + grp;      // 0..B*DI-1
  int d = p & (DI-1);
  int b = p >> 9;
  float A = -__expf(A_log[d*DS_ + s]);
  float Dv = Dp[d];
  float h = 0.f;
  const float* dt_p = dt  + (size_t)b*T_*DI + d;
  const float* u_p  = u   + (size_t)b*T_*DI + d;
  const float* z_p  = xz  + (size_t)b*T_*1024 + DI + d;
  const float* bc_p = dbl + (size_t)b*T_*48;
  float* g_p = g_out + (size_t)b*T_*DI + d;
  #pragma unroll 4
  for (int t = 0; t < T_; t++) {
    float dtv = dt_p[(size_t)t*DI];
    float uv  = u_p[(size_t)t*DI];
    float Bv  = bc_p[(size_t)t*48 + 16 + s];
    float Cv  = bc_p[(size_t)t*48 + 32 + s];
    h = h * __expf(dtv * A) + dtv * uv * Bv;
    float part = h * Cv;
    part += __shfl_xor(part, 8, 16);
    part += __shfl_xor(part, 4, 16);
    part += __shfl_xor(part, 2, 16);
    part += __shfl_xor(part, 1, 16);
    if (s == 0) {
      float zv = z_p[(size_t)t*1024];
      float y = part + uv * Dv;
      g_p[(size_t)t*DI] = y * siluf_(zv);
    }
  }
}

// ---------------- masked mean pool ----------------
__global__ __launch_bounds__(256) void k_pool(
    const float* __restrict__ hln, const int* __restrict__ lengths,
    float* __restrict__ pooled) {
  int b = blockIdx.x;
  int j = threadIdx.x;
  int len = lengths[b];
  if (len < 1) len = 1;
  if (len > T_) len = T_;
  float acc = 0.f;
  for (int t = 0; t < len; t++) acc += hln[((size_t)b*T_ + t)*DM + j];
  pooled[b*DM + j] = acc / (float)len;
}

// ---------------- classifier head ----------------
__global__ __launch_bounds__(128) void k_head(
    const float* __restrict__ pooled, const float* __restrict__ c1w,
    const float* __restrict__ c1b, const float* __restrict__ c2w,
    const float* __restrict__ c2b, float* __restrict__ out) {
  __shared__ float ps[DM];
  __shared__ float z1[128];
  int b = blockIdx.x;
  int j = threadIdx.x;
  ps[j] = pooled[b*DM + j];
  ps[j + 128] = pooled[b*DM + j + 128];
  __syncthreads();
  float acc = c1b[j];
  #pragma unroll 8
  for (int k = 0; k < DM; k++) acc += ps[k] * c1w[j*DM + k];
  z1[j] = siluf_(acc);
  __syncthreads();
  if (j < NC) {
    float o = c2b[j];
    #pragma unroll 8
    for (int k = 0; k < 128; k++) o += z1[k] * c2w[j*128 + k];
    out[b*NC + j] = o;
  }
}

extern "C" void kernel_launch(void* const* d_in, const int* in_sizes, int n_in,
                              void* d_out, int out_size, void* d_ws, size_t ws_size,
                              hipStream_t stream) {
  const float* x       = (const float*)d_in[0];
  const int*   lengths = (const int*)  d_in[1];
  const float* proj_w  = (const float*)d_in[2];
  const float* proj_b  = (const float*)d_in[3];
  const float* p_ln_g  = (const float*)d_in[4];
  const float* p_ln_b  = (const float*)d_in[5];
  const float* ln_g    = (const float*)d_in[6];
  const float* ln_b    = (const float*)d_in[7];
  const float* in_w    = (const float*)d_in[8];
  const float* conv_w  = (const float*)d_in[9];
  const float* conv_b  = (const float*)d_in[10];
  const float* xp_w    = (const float*)d_in[11];
  const float* dt_w    = (const float*)d_in[12];
  const float* dt_b    = (const float*)d_in[13];
  const float* A_log   = (const float*)d_in[14];
  const float* Dp      = (const float*)d_in[15];
  const float* out_w   = (const float*)d_in[16];
  const float* pre_g   = (const float*)d_in[17];
  const float* pre_b   = (const float*)d_in[18];
  const float* c1_w    = (const float*)d_in[19];
  const float* c1_b    = (const float*)d_in[20];
  const float* c2_w    = (const float*)d_in[21];
  const float* c2_b    = (const float*)d_in[22];
  float* out = (float*)d_out;

  float* ws  = (float*)d_ws;
  float* h      = ws;                                   // NTOK*DM
  float* xln    = h    + (size_t)NTOK*DM;               // NTOK*DM
  float* xz     = xln  + (size_t)NTOK*DM;               // NTOK*1024
  float* u      = xz   + (size_t)NTOK*1024;             // NTOK*DI
  float* dbl    = u    + (size_t)NTOK*DI;               // NTOK*48
  float* dtb    = dbl  + (size_t)NTOK*48;               // NTOK*DI (dt, then g in-place)
  float* pooled = dtb  + (size_t)NTOK*DI;               // B*DM

  k_proj_ln<<<NTOK, 256, 0, stream>>>(x, proj_w, proj_b, p_ln_g, p_ln_b, h);

  for (int l = 0; l < NL; l++) {
    k_ln<<<NTOK, 256, 0, stream>>>(h, ln_g + l*DM, ln_b + l*DM, xln);

    dim3 g_in(NTOK/64, 1024/64);
    k_gemm<0,0><<<g_in, 256, 0, stream>>>(xln, in_w + (size_t)l*1024*DM, nullptr,
                                          xz, NTOK, 1024, DM, DM);

    k_conv_silu<<<(NTOK*DI)/256, 256, 0, stream>>>(xz, conv_w + l*DI*4, conv_b + l*DI, u);

    dim3 g_xp(NTOK/64, 1);
    k_gemm<0,0><<<g_xp, 256, 0, stream>>>(u, xp_w + (size_t)l*48*DI, nullptr,
                                          dbl, NTOK, 48, DI, DI);

    dim3 g_dt(NTOK/64, DI/64);
    k_gemm<1,0><<<g_dt, 256, 0, stream>>>(dbl, dt_w + (size_t)l*DI*16, dt_b + l*DI,
                                          dtb, NTOK, DI, 16, 48);

    k_scan<<<(B_*DI)/16, 256, 0, stream>>>(dtb, u, dbl, xz,
                                           A_log + (size_t)l*DI*DS_, Dp + l*DI, dtb);

    dim3 g_out(NTOK/64, DM/64);
    k_gemm<0,1><<<g_out, 256, 0, stream>>>(dtb, out_w + (size_t)l*DM*DI, nullptr,
                                           h, NTOK, DM, DI, DI);
  }

  k_ln<<<NTOK, 256, 0, stream>>>(h, pre_g, pre_b, xln);
  k_pool<<<B_, 256, 0, stream>>>(xln, lengths, pooled);
  k_head<<<B_, 128, 0, stream>>>(pooled, c1_w, c1_b, c2_w, c2_b, out);
}

// Round 2
// 3036.435 us; speedup vs baseline: 1.6450x; 1.6450x over previous
//
#include <hip/hip_runtime.h>
#include <math.h>

#define B_ 16
#define T_ 512
#define FEAT_ 40
#define DM 256
#define DI 512
#define DS_ 16
#define NL 8
#define NC 35
#define NTOK (B_*T_)
#define NCHUNK 16
#define CLEN (T_/NCHUNK)   // 32

__device__ __forceinline__ float sigmoidf_(float x){ return 1.f/(1.f+__expf(-x)); }
__device__ __forceinline__ float siluf_(float x){ return x*sigmoidf_(x); }

// block-wide (256 threads) sum; red must have 8 floats; slot = 0 or 1
__device__ __forceinline__ float blocksum256(float v, float* red, int slot) {
  #pragma unroll
  for (int off = 32; off > 0; off >>= 1) v += __shfl_down(v, off, 64);
  int lane = threadIdx.x & 63, wid = threadIdx.x >> 6;
  if (lane == 0) red[slot*4 + wid] = v;
  __syncthreads();
  return red[slot*4+0]+red[slot*4+1]+red[slot*4+2]+red[slot*4+3];
}

// ---------------- input projection + LN + silu ----------------
__global__ __launch_bounds__(256) void k_proj_ln(
    const float* __restrict__ x, const float* __restrict__ pw,
    const float* __restrict__ pb, const float* __restrict__ g,
    const float* __restrict__ be, float* __restrict__ h) {
  __shared__ float xs[FEAT_];
  __shared__ float red[8];
  int tok = blockIdx.x;
  int j = threadIdx.x;
  if (j < FEAT_) xs[j] = x[tok*FEAT_ + j];
  __syncthreads();
  float acc = pb[j];
  #pragma unroll
  for (int k = 0; k < FEAT_; k++) acc += xs[k] * pw[j*FEAT_ + k];
  float m = blocksum256(acc, red, 0) * (1.f/DM);
  float d = acc - m;
  float var = blocksum256(d*d, red, 1) * (1.f/DM);
  float v = d * rsqrtf(var + 1e-5f) * g[j] + be[j];
  h[tok*DM + j] = siluf_(v);
}

// ---------------- layernorm over DM ----------------
__global__ __launch_bounds__(256) void k_ln(
    const float* __restrict__ in, const float* __restrict__ g,
    const float* __restrict__ be, float* __restrict__ outp) {
  __shared__ float red[8];
  int tok = blockIdx.x;
  int j = threadIdx.x;
  float v = in[tok*DM + j];
  float m = blocksum256(v, red, 0) * (1.f/DM);
  float d = v - m;
  float var = blocksum256(d*d, red, 1) * (1.f/DM);
  outp[tok*DM + j] = d * rsqrtf(var + 1e-5f) * g[j] + be[j];
}

// ---------------- generic tiled f32 GEMM: C = act(A @ W^T + bias) ----------------
template<int ACT, int RESID>
__global__ __launch_bounds__(256) void k_gemm(
    const float* __restrict__ A, const float* __restrict__ W,
    const float* __restrict__ bias, float* __restrict__ C,
    int M, int N, int K, int lda) {
  __shared__ __align__(16) float As[16][68];
  __shared__ __align__(16) float Ws[16][68];
  int tid = threadIdx.x;
  int tx = tid & 15, ty = tid >> 4;
  int m0 = blockIdx.x * 64, n0 = blockIdx.y * 64;
  int lk = tid & 15;   // k within tile
  int lr = tid >> 4;   // row base
  float acc[4][4] = {};
  for (int k0 = 0; k0 < K; k0 += 16) {
    #pragma unroll
    for (int i = 0; i < 4; i++) {
      int m = m0 + lr + i*16;
      As[lk][lr + i*16] = A[(size_t)m*lda + k0 + lk];
    }
    #pragma unroll
    for (int i = 0; i < 4; i++) {
      int n = n0 + lr + i*16;
      Ws[lk][lr + i*16] = (n < N) ? W[(size_t)n*K + k0 + lk] : 0.f;
    }
    __syncthreads();
    #pragma unroll
    for (int kk = 0; kk < 16; kk++) {
      float a[4], b[4];
      #pragma unroll
      for (int i = 0; i < 4; i++) a[i] = As[kk][ty*4 + i];
      #pragma unroll
      for (int j = 0; j < 4; j++) b[j] = Ws[kk][tx*4 + j];
      #pragma unroll
      for (int i = 0; i < 4; i++)
        #pragma unroll
        for (int j = 0; j < 4; j++)
          acc[i][j] += a[i] * b[j];
    }
    __syncthreads();
  }
  #pragma unroll
  for (int i = 0; i < 4; i++) {
    int m = m0 + ty*4 + i;
    #pragma unroll
    for (int j = 0; j < 4; j++) {
      int n = n0 + tx*4 + j;
      if (n < N) {
        float v = acc[i][j];
        if (bias) v += bias[n];
        if (ACT == 1) v = (v > 20.f) ? v : log1pf(__expf(v));
        if (RESID) C[(size_t)m*N + n] += v;
        else       C[(size_t)m*N + n] = v;
      }
    }
  }
}

// ---------------- depthwise causal conv (k=4) + silu ----------------
__global__ __launch_bounds__(256) void k_conv_silu(
    const float* __restrict__ xz, const float* __restrict__ w,
    const float* __restrict__ bias, float* __restrict__ u) {
  int idx = blockIdx.x * 256 + threadIdx.x;   // b*T*DI
  int d = idx & (DI-1);
  int t = (idx >> 9) & (T_-1);
  int b = idx >> 18;
  const float* base = xz + (size_t)b * T_ * 1024;
  float acc = bias[d];
  #pragma unroll
  for (int j = 0; j < 4; j++) {
    int tt = t - 3 + j;
    if (tt >= 0) acc += w[d*4 + j] * base[(size_t)tt*1024 + d];
  }
  u[idx] = siluf_(acc);
}

// ---------------- chunked parallel selective scan ----------------
// Pass A: per (b, chunk, d, s): P = prod(dA), Q = chunk-local scan from h=0.
// gid = b*(NCHUNK*DI) + c*DI + d   (d fastest for coalescing)
__global__ __launch_bounds__(256) void k_scan_part(
    const float* __restrict__ dt, const float* __restrict__ u,
    const float* __restrict__ dbl, const float* __restrict__ A_log,
    float* __restrict__ P, float* __restrict__ Q) {
  int tid = threadIdx.x;
  int s = tid & 15;
  int gid = blockIdx.x * 16 + (tid >> 4);
  int d = gid & (DI-1);
  int c = (gid >> 9) & (NCHUNK-1);
  int b = gid >> 13;
  float A = -__expf(A_log[d*DS_ + s]);
  size_t tokbase = (size_t)b*T_ + c*CLEN;
  const float* dt_p = dt + tokbase*DI + d;
  const float* u_p  = u  + tokbase*DI + d;
  const float* bc_p = dbl + tokbase*48 + 16 + s;
  float Pv = 1.f, Qv = 0.f;
  #pragma unroll 8
  for (int t = 0; t < CLEN; t++) {
    float dtv = dt_p[(size_t)t*DI];
    float uv  = u_p[(size_t)t*DI];
    float Bv  = bc_p[(size_t)t*48];
    float dA = __expf(dtv * A);
    Pv *= dA;
    Qv = Qv*dA + dtv*uv*Bv;
  }
  size_t oi = (((size_t)b*NCHUNK + c)*DI + d)*DS_ + s;
  P[oi] = Pv;
  Q[oi] = Qv;
}

// Pass B: per (b,d,s): sequentially combine chunk summaries; overwrite Q with
// the chunk-START state H_c.
__global__ __launch_bounds__(256) void k_scan_combine(
    const float* __restrict__ P, float* __restrict__ Q) {
  int p = blockIdx.x * 256 + threadIdx.x;   // B*DI*DS threads
  int s = p & 15;
  int d = (p >> 4) & (DI-1);
  int b = p >> 13;
  float H = 0.f;
  #pragma unroll
  for (int c = 0; c < NCHUNK; c++) {
    size_t oi = (((size_t)b*NCHUNK + c)*DI + d)*DS_ + s;
    float Pc = P[oi], Qc = Q[oi];
    Q[oi] = H;
    H = Pc*H + Qc;
  }
}

// Pass C: re-run each chunk from its start state; y = sum_s h*C (shfl reduce);
// fuse +u*Dp and *silu(z); write g into xz columns [0,DI) (dead after conv).
__global__ __launch_bounds__(256) void k_scan_final(
    const float* __restrict__ dt, const float* __restrict__ u,
    const float* __restrict__ dbl, const float* __restrict__ xz_z,
    const float* __restrict__ A_log, const float* __restrict__ Dp,
    const float* __restrict__ Hs, float* __restrict__ g_out) {
  int tid = threadIdx.x;
  int s = tid & 15;
  int gid = blockIdx.x * 16 + (tid >> 4);
  int d = gid & (DI-1);
  int c = (gid >> 9) & (NCHUNK-1);
  int b = gid >> 13;
  float A = -__expf(A_log[d*DS_ + s]);
  float Dv = Dp[d];
  size_t tokbase = (size_t)b*T_ + c*CLEN;
  const float* dt_p = dt + tokbase*DI + d;
  const float* u_p  = u  + tokbase*DI + d;
  const float* bc_p = dbl + tokbase*48 + 16 + s;
  const float* cc_p = dbl + tokbase*48 + 32 + s;
  const float* z_p  = xz_z + tokbase*1024 + DI + d;
  float* g_p = g_out + tokbase*1024 + d;
  size_t oi = (((size_t)b*NCHUNK + c)*DI + d)*DS_ + s;
  float h = Hs[oi];
  #pragma unroll 4
  for (int t = 0; t < CLEN; t++) {
    float dtv = dt_p[(size_t)t*DI];
    float uv  = u_p[(size_t)t*DI];
    float Bv  = bc_p[(size_t)t*48];
    float Cv  = cc_p[(size_t)t*48];
    float dA = __expf(dtv * A);
    h = h*dA + dtv*uv*Bv;
    float part = h * Cv;
    part += __shfl_xor(part, 8, 16);
    part += __shfl_xor(part, 4, 16);
    part += __shfl_xor(part, 2, 16);
    part += __shfl_xor(part, 1, 16);
    if (s == 0) {
      float zv = z_p[(size_t)t*1024];
      float y = part + uv * Dv;
      g_p[(size_t)t*1024] = y * siluf_(zv);
    }
  }
}

// ---------------- masked mean pool ----------------
__global__ __launch_bounds__(256) void k_pool(
    const float* __restrict__ hln, const int* __restrict__ lengths,
    float* __restrict__ pooled) {
  int b = blockIdx.x;
  int j = threadIdx.x;
  int len = lengths[b];
  if (len < 1) len = 1;
  if (len > T_) len = T_;
  float acc = 0.f;
  for (int t = 0; t < len; t++) acc += hln[((size_t)b*T_ + t)*DM + j];
  pooled[b*DM + j] = acc / (float)len;
}

// ---------------- classifier head ----------------
__global__ __launch_bounds__(128) void k_head(
    const float* __restrict__ pooled, const float* __restrict__ c1w,
    const float* __restrict__ c1b, const float* __restrict__ c2w,
    const float* __restrict__ c2b, float* __restrict__ out) {
  __shared__ float ps[DM];
  __shared__ float z1[128];
  int b = blockIdx.x;
  int j = threadIdx.x;
  ps[j] = pooled[b*DM + j];
  ps[j + 128] = pooled[b*DM + j + 128];
  __syncthreads();
  float acc = c1b[j];
  #pragma unroll 8
  for (int k = 0; k < DM; k++) acc += ps[k] * c1w[j*DM + k];
  z1[j] = siluf_(acc);
  __syncthreads();
  if (j < NC) {
    float o = c2b[j];
    #pragma unroll 8
    for (int k = 0; k < 128; k++) o += z1[k] * c2w[j*128 + k];
    out[b*NC + j] = o;
  }
}

extern "C" void kernel_launch(void* const* d_in, const int* in_sizes, int n_in,
                              void* d_out, int out_size, void* d_ws, size_t ws_size,
                              hipStream_t stream) {
  const float* x       = (const float*)d_in[0];
  const int*   lengths = (const int*)  d_in[1];
  const float* proj_w  = (const float*)d_in[2];
  const float* proj_b  = (const float*)d_in[3];
  const float* p_ln_g  = (const float*)d_in[4];
  const float* p_ln_b  = (const float*)d_in[5];
  const float* ln_g    = (const float*)d_in[6];
  const float* ln_b    = (const float*)d_in[7];
  const float* in_w    = (const float*)d_in[8];
  const float* conv_w  = (const float*)d_in[9];
  const float* conv_b  = (const float*)d_in[10];
  const float* xp_w    = (const float*)d_in[11];
  const float* dt_w    = (const float*)d_in[12];
  const float* dt_b    = (const float*)d_in[13];
  const float* A_log   = (const float*)d_in[14];
  const float* Dp      = (const float*)d_in[15];
  const float* out_w   = (const float*)d_in[16];
  const float* pre_g   = (const float*)d_in[17];
  const float* pre_b   = (const float*)d_in[18];
  const float* c1_w    = (const float*)d_in[19];
  const float* c1_b    = (const float*)d_in[20];
  const float* c2_w    = (const float*)d_in[21];
  const float* c2_b    = (const float*)d_in[22];
  float* out = (float*)d_out;

  float* ws  = (float*)d_ws;
  float* h      = ws;                                   // NTOK*DM
  float* xln    = h    + (size_t)NTOK*DM;               // NTOK*DM (also reused as P)
  float* xz     = xln  + (size_t)NTOK*DM;               // NTOK*1024 (cols 0..511 reused as g)
  float* u      = xz   + (size_t)NTOK*1024;             // NTOK*DI
  float* dbl    = u    + (size_t)NTOK*DI;               // NTOK*48
  float* dtb    = dbl  + (size_t)NTOK*48;               // NTOK*DI
  float* pooled = dtb  + (size_t)NTOK*DI;               // B*DM
  float* Qbuf   = pooled + (size_t)B_*DM;               // B*NCHUNK*DI*DS
  float* Pbuf   = xln;                                  // reuse (dead during scan)

  k_proj_ln<<<NTOK, 256, 0, stream>>>(x, proj_w, proj_b, p_ln_g, p_ln_b, h);

  for (int l = 0; l < NL; l++) {
    k_ln<<<NTOK, 256, 0, stream>>>(h, ln_g + l*DM, ln_b + l*DM, xln);

    dim3 g_in(NTOK/64, 1024/64);
    k_gemm<0,0><<<g_in, 256, 0, stream>>>(xln, in_w + (size_t)l*1024*DM, nullptr,
                                          xz, NTOK, 1024, DM, DM);

    k_conv_silu<<<(NTOK*DI)/256, 256, 0, stream>>>(xz, conv_w + l*DI*4, conv_b + l*DI, u);

    dim3 g_xp(NTOK/64, 1);
    k_gemm<0,0><<<g_xp, 256, 0, stream>>>(u, xp_w + (size_t)l*48*DI, nullptr,
                                          dbl, NTOK, 48, DI, DI);

    dim3 g_dt(NTOK/64, DI/64);
    k_gemm<1,0><<<g_dt, 256, 0, stream>>>(dbl, dt_w + (size_t)l*DI*16, dt_b + l*DI,
                                          dtb, NTOK, DI, 16, 48);

    // chunked parallel scan
    k_scan_part<<<(B_*NCHUNK*DI)/16, 256, 0, stream>>>(
        dtb, u, dbl, A_log + (size_t)l*DI*DS_, Pbuf, Qbuf);
    k_scan_combine<<<(B_*DI*DS_)/256, 256, 0, stream>>>(Pbuf, Qbuf);
    k_scan_final<<<(B_*NCHUNK*DI)/16, 256, 0, stream>>>(
        dtb, u, dbl, xz, A_log + (size_t)l*DI*DS_, Dp + l*DI, Qbuf, xz);

    dim3 g_out(NTOK/64, DM/64);
    k_gemm<0,1><<<g_out, 256, 0, stream>>>(xz, out_w + (size_t)l*DM*DI, nullptr,
                                           h, NTOK, DM, DI, 1024);
  }

  k_ln<<<NTOK, 256, 0, stream>>>(h, pre_g, pre_b, xln);
  k_pool<<<B_, 256, 0, stream>>>(xln, lengths, pooled);
  k_head<<<B_, 128, 0, stream>>>(pooled, c1_w, c1_b, c2_w, c2_b, out);
}

// Round 3
// 1360.563 us; speedup vs baseline: 3.6711x; 2.2317x over previous
//
#include <hip/hip_runtime.h>
#include <hip/hip_bf16.h>
#include <math.h>

#define B_ 16
#define T_ 512
#define FEAT_ 40
#define DM 256
#define DI 512
#define DS_ 16
#define NL 8
#define NC 35
#define NTOK (B_*T_)
#define NCHUNK 16
#define CLEN (T_/NCHUNK)   // 32

typedef __attribute__((ext_vector_type(8))) short bf16x8;
typedef __attribute__((ext_vector_type(4))) float f32x4;

__device__ __forceinline__ float sigmoidf_(float x){ return 1.f/(1.f+__expf(-x)); }
__device__ __forceinline__ float siluf_(float x){ return x*sigmoidf_(x); }

// ---------------- f32 -> bf16 bulk convert ----------------
__global__ __launch_bounds__(256) void k_cvt(
    const float* __restrict__ src, __hip_bfloat16* __restrict__ dst, int n) {
  int i = blockIdx.x * 256 + threadIdx.x;
  if (i < n) dst[i] = __float2bfloat16(src[i]);
}

// ---------------- build combined xp/dt weight (bf16) ----------------
// rows 0..511: W[n][k] = sum_r dt_w[l][n][r] * xp_w[l][r][k]   (dt path folded)
// rows 512..543: xp_w rows 16..47 (B then C)
__global__ __launch_bounds__(256) void k_comb(
    const float* __restrict__ dt_w, const float* __restrict__ xp_w,
    __hip_bfloat16* __restrict__ W) {
  int l = blockIdx.x / 544, n = blockIdx.x % 544;
  const float* xw = xp_w + (size_t)l*48*512;
  __hip_bfloat16* dst = W + ((size_t)l*544 + n)*512;
  int k = threadIdx.x;
  float a0, a1;
  if (n < 512) {
    const float* dw = dt_w + ((size_t)l*512 + n)*16;
    a0 = 0.f; a1 = 0.f;
    #pragma unroll
    for (int r = 0; r < 16; r++) {
      float c = dw[r];
      a0 += c * xw[r*512 + k];
      a1 += c * xw[r*512 + k + 256];
    }
  } else {
    a0 = xw[(16 + (n-512))*512 + k];
    a1 = xw[(16 + (n-512))*512 + k + 256];
  }
  dst[k]       = __float2bfloat16(a0);
  dst[k + 256] = __float2bfloat16(a1);
}

// ---------------- input projection + LN + silu (f32 out) ----------------
__global__ __launch_bounds__(256) void k_proj_ln(
    const float* __restrict__ x, const float* __restrict__ pw,
    const float* __restrict__ pb, const float* __restrict__ g,
    const float* __restrict__ be, float* __restrict__ h) {
  __shared__ float xs[FEAT_];
  __shared__ float red[8];
  int tok = blockIdx.x;
  int j = threadIdx.x;
  if (j < FEAT_) xs[j] = x[tok*FEAT_ + j];
  __syncthreads();
  float acc = pb[j];
  #pragma unroll
  for (int k = 0; k < FEAT_; k++) acc += xs[k] * pw[j*FEAT_ + k];
  float v = acc;
  #pragma unroll
  for (int off = 32; off > 0; off >>= 1) v += __shfl_down(v, off, 64);
  int lane = threadIdx.x & 63, wid = threadIdx.x >> 6;
  if (lane == 0) red[wid] = v;
  __syncthreads();
  float m = (red[0]+red[1]+red[2]+red[3]) * (1.f/DM);
  float d = acc - m;
  float q = d*d;
  #pragma unroll
  for (int off = 32; off > 0; off >>= 1) q += __shfl_down(q, off, 64);
  if (lane == 0) red[4+wid] = q;
  __syncthreads();
  float var = (red[4]+red[5]+red[6]+red[7]) * (1.f/DM);
  float o = d * rsqrtf(var + 1e-5f) * g[j] + be[j];
  h[tok*DM + j] = siluf_(o);
}

// ---------------- LayerNorm over DM, writes bf16 (wave per token) ----------------
__global__ __launch_bounds__(256) void k_ln_bf(
    const float* __restrict__ in, const float* __restrict__ g,
    const float* __restrict__ be, __hip_bfloat16* __restrict__ outp) {
  int wid = threadIdx.x >> 6, lane = threadIdx.x & 63;
  size_t tok = (size_t)blockIdx.x*4 + wid;
  float4 v = *(const float4*)(in + tok*DM + lane*4);
  float s = v.x + v.y + v.z + v.w;
  #pragma unroll
  for (int off = 32; off > 0; off >>= 1) s += __shfl_xor(s, off);
  float m = s * (1.f/DM);
  float dx = v.x-m, dy = v.y-m, dz = v.z-m, dw = v.w-m;
  float q = dx*dx + dy*dy + dz*dz + dw*dw;
  #pragma unroll
  for (int off = 32; off > 0; off >>= 1) q += __shfl_xor(q, off);
  float r = rsqrtf(q*(1.f/DM) + 1e-5f);
  float4 gg = *(const float4*)(g + lane*4);
  float4 bb = *(const float4*)(be + lane*4);
  __hip_bfloat16 o[4];
  o[0] = __float2bfloat16(dx*r*gg.x + bb.x);
  o[1] = __float2bfloat16(dy*r*gg.y + bb.y);
  o[2] = __float2bfloat16(dz*r*gg.z + bb.z);
  o[3] = __float2bfloat16(dw*r*gg.w + bb.w);
  *(short4*)(outp + tok*DM + lane*4) = *(const short4*)o;
}

// ---------------- bf16 MFMA GEMM: C = A(MxK) @ W(NxK)^T ----------------
// 128x128 tile, BK=32, 256 threads (4 waves, 2x2 of 64x64), 16x16x32 MFMA.
// EPI: 0 plain store (ldC), 1 resid += (ldC), 2 dbl2 (ldC=544, softplus+bias n<512,
//      guard n<N), 3 split (n<512 -> C ld512, n>=512 -> C2 ld512)
template<int EPI>
__global__ __launch_bounds__(256) void k_mfma(
    const short* __restrict__ A, const short* __restrict__ W,
    const float* __restrict__ bias, float* __restrict__ C,
    float* __restrict__ C2, int N, int K, int ldA, int ldC) {
  __shared__ __align__(16) short As[128*32];
  __shared__ __align__(16) short Bs[128*32];
  int tid = threadIdx.x;
  int wave = tid >> 6, lane = tid & 63;
  int m0 = blockIdx.x * 128, n0 = blockIdx.y * 128;
  int wr = wave >> 1, wc = wave & 1;
  f32x4 acc[4][4] = {};

  int srow = wave*32 + (lane >> 2);
  int scol = (lane & 3) * 8;                  // shorts (16B per lane)
  const short* Ag = A + (size_t)(m0 + srow)*ldA + scol;
  const short* Wg = W + (size_t)(n0 + srow)*K  + scol;
  short* Asl = &As[(wave*32)*32];
  short* Bsl = &Bs[(wave*32)*32];
  int lr = lane & 15, lk = lane >> 4;

  for (int k0 = 0; k0 < K; k0 += 32) {
    #pragma unroll
    for (int j = 0; j < 2; j++) {
      __builtin_amdgcn_global_load_lds(
        (const __attribute__((address_space(1))) unsigned int*)(Ag + (size_t)j*16*ldA + k0),
        (__attribute__((address_space(3))) unsigned int*)(Asl + j*16*32), 16, 0, 0);
      __builtin_amdgcn_global_load_lds(
        (const __attribute__((address_space(1))) unsigned int*)(Wg + (size_t)j*16*K + k0),
        (__attribute__((address_space(3))) unsigned int*)(Bsl + j*16*32), 16, 0, 0);
    }
    asm volatile("s_waitcnt vmcnt(0)" ::: "memory");
    __syncthreads();
    bf16x8 af[4], bfr[4];
    #pragma unroll
    for (int i = 0; i < 4; i++) {
      af[i]  = *(const bf16x8*)&As[(wr*64 + i*16 + lr)*32 + lk*8];
      bfr[i] = *(const bf16x8*)&Bs[(wc*64 + i*16 + lr)*32 + lk*8];
    }
    #pragma unroll
    for (int i = 0; i < 4; i++)
      #pragma unroll
      for (int j = 0; j < 4; j++)
        acc[i][j] = __builtin_amdgcn_mfma_f32_16x16x32_bf16(af[i], bfr[j], acc[i][j], 0, 0, 0);
    __syncthreads();
  }

  #pragma unroll
  for (int i = 0; i < 4; i++) {
    int mrow = m0 + wr*64 + i*16 + lk*4;
    #pragma unroll
    for (int j = 0; j < 4; j++) {
      int n = n0 + wc*64 + j*16 + lr;
      f32x4 v = acc[i][j];
      #pragma unroll
      for (int q = 0; q < 4; q++) {
        size_t m = (size_t)(mrow + q);
        if (EPI == 0) {
          C[m*ldC + n] = v[q];
        } else if (EPI == 1) {
          C[m*ldC + n] += v[q];
        } else if (EPI == 2) {
          if (n < N) {
            float w = v[q];
            if (n < 512) { w += bias[n]; w = (w > 20.f) ? w : log1pf(__expf(w)); }
            C[m*544 + n] = w;
          }
        } else {
          if (n < 512) C[m*512 + n] = v[q];
          else         C2[m*512 + (n-512)] = v[q];
        }
      }
    }
  }
}

// ---------------- depthwise causal conv (k=4) + silu; writes f32 + bf16 ----------------
__global__ __launch_bounds__(256) void k_conv_silu(
    const float* __restrict__ upre, const float* __restrict__ w,
    const float* __restrict__ bias, float* __restrict__ u,
    __hip_bfloat16* __restrict__ u_bf) {
  int idx = blockIdx.x * 256 + threadIdx.x;   // b*T*DI
  int d = idx & (DI-1);
  int t = (idx >> 9) & (T_-1);
  int b = idx >> 18;
  const float* base = upre + (size_t)b * T_ * DI;
  float acc = bias[d];
  #pragma unroll
  for (int j = 0; j < 4; j++) {
    int tt = t - 3 + j;
    if (tt >= 0) acc += w[d*4 + j] * base[(size_t)tt*DI + d];
  }
  float s = siluf_(acc);
  u[idx] = s;
  u_bf[idx] = __float2bfloat16(s);
}

// ---------------- fused chunked selective scan ----------------
// block = 256 threads = 16 d x 16 chunks; 16 states per thread in registers.
__global__ __launch_bounds__(256) void k_scan_f(
    const float* __restrict__ dbl2, const float* __restrict__ u,
    const float* __restrict__ zbuf, const float* __restrict__ A_log,
    const float* __restrict__ Dp, __hip_bfloat16* __restrict__ g_bf) {
  __shared__ float Pl[256*17];
  __shared__ float Ql[256*17];
  int tid = threadIdx.x;
  int dloc = tid & 15, c = tid >> 4;
  int d = (blockIdx.x & 31) * 16 + dloc;
  int b = blockIdx.x >> 5;

  float Av[16];
  #pragma unroll
  for (int s4 = 0; s4 < 4; s4++) {
    float4 al = *(const float4*)(A_log + d*16 + s4*4);
    Av[s4*4+0] = -__expf(al.x);
    Av[s4*4+1] = -__expf(al.y);
    Av[s4*4+2] = -__expf(al.z);
    Av[s4*4+3] = -__expf(al.w);
  }
  size_t tokbase = (size_t)b*T_ + c*CLEN;

  // pass A: chunk-local P (prod dA) and Q (scan from 0)
  {
    const float*  dtp = dbl2 + tokbase*544 + d;
    const float*  up  = u    + tokbase*512 + d;
    const float4* bp  = (const float4*)(dbl2 + tokbase*544 + 512);
    float P[16], Q[16];
    #pragma unroll
    for (int s = 0; s < 16; s++) { P[s] = 1.f; Q[s] = 0.f; }
    for (int t = 0; t < CLEN; t++) {
      float dtv = *dtp, uv = *up;
      float du = dtv * uv;
      float4 b0 = bp[0], b1 = bp[1], b2 = bp[2], b3 = bp[3];
      float barr[16] = {b0.x,b0.y,b0.z,b0.w, b1.x,b1.y,b1.z,b1.w,
                        b2.x,b2.y,b2.z,b2.w, b3.x,b3.y,b3.z,b3.w};
      #pragma unroll
      for (int s = 0; s < 16; s++) {
        float dA = __expf(dtv * Av[s]);
        P[s] *= dA;
        Q[s] = Q[s]*dA + du*barr[s];
      }
      dtp += 544; up += 512; bp += 136;
    }
    #pragma unroll
    for (int s = 0; s < 16; s++) { Pl[tid*17+s] = P[s]; Ql[tid*17+s] = Q[s]; }
  }
  __syncthreads();

  // combine: threads re-roled as (dloc, s); walk 16 chunks, leave start-state in Ql
  {
    int dl = tid & 15, s2 = tid >> 4;
    float H = 0.f;
    #pragma unroll
    for (int cc = 0; cc < NCHUNK; cc++) {
      int row = cc*16 + dl;
      float Pc = Pl[row*17 + s2];
      float Qc = Ql[row*17 + s2];
      Ql[row*17 + s2] = H;
      H = Pc*H + Qc;
    }
  }
  __syncthreads();

  // pass C: rerun chunk from start state, y = in-register dot over 16 states
  {
    float h[16];
    #pragma unroll
    for (int s = 0; s < 16; s++) h[s] = Ql[tid*17 + s];
    const float*  dtp = dbl2 + tokbase*544 + d;
    const float*  up  = u    + tokbase*512 + d;
    const float4* bp  = (const float4*)(dbl2 + tokbase*544 + 512);
    const float4* cp  = (const float4*)(dbl2 + tokbase*544 + 528);
    const float*  zp  = zbuf + tokbase*512 + d;
    __hip_bfloat16* gp = g_bf + tokbase*512 + d;
    float Dv = Dp[d];
    for (int t = 0; t < CLEN; t++) {
      float dtv = *dtp, uv = *up;
      float du = dtv * uv;
      float4 b0 = bp[0], b1 = bp[1], b2 = bp[2], b3 = bp[3];
      float4 c0 = cp[0], c1 = cp[1], c2 = cp[2], c3 = cp[3];
      float barr[16] = {b0.x,b0.y,b0.z,b0.w, b1.x,b1.y,b1.z,b1.w,
                        b2.x,b2.y,b2.z,b2.w, b3.x,b3.y,b3.z,b3.w};
      float carr[16] = {c0.x,c0.y,c0.z,c0.w, c1.x,c1.y,c1.z,c1.w,
                        c2.x,c2.y,c2.z,c2.w, c3.x,c3.y,c3.z,c3.w};
      float y = 0.f;
      #pragma unroll
      for (int s = 0; s < 16; s++) {
        float dA = __expf(dtv * Av[s]);
        h[s] = h[s]*dA + du*barr[s];
        y += h[s]*carr[s];
      }
      float zv = *zp;
      float gg = (y + uv*Dv) * siluf_(zv);
      *gp = __float2bfloat16(gg);
      dtp += 544; up += 512; bp += 136; cp += 136; zp += 512; gp += 512;
    }
  }
}

// ---------------- masked mean pool (reads bf16) ----------------
__global__ __launch_bounds__(256) void k_pool(
    const __hip_bfloat16* __restrict__ hln, const int* __restrict__ lengths,
    float* __restrict__ pooled) {
  int b = blockIdx.x;
  int j = threadIdx.x;
  int len = lengths[b];
  if (len < 1) len = 1;
  if (len > T_) len = T_;
  float acc = 0.f;
  for (int t = 0; t < len; t++) acc += __bfloat162float(hln[((size_t)b*T_ + t)*DM + j]);
  pooled[b*DM + j] = acc / (float)len;
}

// ---------------- classifier head ----------------
__global__ __launch_bounds__(128) void k_head(
    const float* __restrict__ pooled, const float* __restrict__ c1w,
    const float* __restrict__ c1b, const float* __restrict__ c2w,
    const float* __restrict__ c2b, float* __restrict__ out) {
  __shared__ float ps[DM];
  __shared__ float z1[128];
  int b = blockIdx.x;
  int j = threadIdx.x;
  ps[j] = pooled[b*DM + j];
  ps[j + 128] = pooled[b*DM + j + 128];
  __syncthreads();
  float acc = c1b[j];
  #pragma unroll 8
  for (int k = 0; k < DM; k++) acc += ps[k] * c1w[j*DM + k];
  z1[j] = siluf_(acc);
  __syncthreads();
  if (j < NC) {
    float o = c2b[j];
    #pragma unroll 8
    for (int k = 0; k < 128; k++) o += z1[k] * c2w[j*128 + k];
    out[b*NC + j] = o;
  }
}

extern "C" void kernel_launch(void* const* d_in, const int* in_sizes, int n_in,
                              void* d_out, int out_size, void* d_ws, size_t ws_size,
                              hipStream_t stream) {
  const float* x       = (const float*)d_in[0];
  const int*   lengths = (const int*)  d_in[1];
  const float* proj_w  = (const float*)d_in[2];
  const float* proj_b  = (const float*)d_in[3];
  const float* p_ln_g  = (const float*)d_in[4];
  const float* p_ln_b  = (const float*)d_in[5];
  const float* ln_g    = (const float*)d_in[6];
  const float* ln_b    = (const float*)d_in[7];
  const float* in_w    = (const float*)d_in[8];
  const float* conv_w  = (const float*)d_in[9];
  const float* conv_b  = (const float*)d_in[10];
  const float* xp_w    = (const float*)d_in[11];
  const float* dt_w    = (const float*)d_in[12];
  const float* dt_b    = (const float*)d_in[13];
  const float* A_log   = (const float*)d_in[14];
  const float* Dp      = (const float*)d_in[15];
  const float* out_w   = (const float*)d_in[16];
  const float* pre_g   = (const float*)d_in[17];
  const float* pre_b   = (const float*)d_in[18];
  const float* c1_w    = (const float*)d_in[19];
  const float* c1_b    = (const float*)d_in[20];
  const float* c2_w    = (const float*)d_in[21];
  const float* c2_b    = (const float*)d_in[22];
  float* out = (float*)d_out;

  // ---- workspace layout (bytes), total ~75.3 MiB ----
  char* base = (char*)d_ws;
  __hip_bfloat16* xpcW   = (__hip_bfloat16*)(base + 0);           // 8*544*512*2 (tile overrun lands in inW: safe)
  __hip_bfloat16* inW    = (__hip_bfloat16*)(base + 4456448);     // 8*1024*256*2
  __hip_bfloat16* outW   = (__hip_bfloat16*)(base + 8650752);     // 8*256*512*2
  __hip_bfloat16* act    = (__hip_bfloat16*)(base + 10747904);    // 8192*512*2 (xln_bf / u_bf / g_bf)
  float*          h_res  = (float*)(base + 19136512);             // 8192*256*4
  float*          zbuf   = (float*)(base + 27525120);             // 8192*512*4
  float*          updbl  = (float*)(base + 44302336);             // 8192*544*4 (upre then dbl2)
  float*          u      = (float*)(base + 62128128);             // 8192*512*4
  float*          pooled = (float*)(base + 78905344);             // 16*256*4

  float* upre = updbl;   // row stride 512, first 16 MiB of updbl
  float* dbl2 = updbl;   // row stride 544

  // ---- weight preprocessing (every launch; deterministic) ----
  k_cvt<<<(8*1024*256)/256, 256, 0, stream>>>(in_w, inW, 8*1024*256);
  k_cvt<<<(8*256*512)/256, 256, 0, stream>>>(out_w, outW, 8*256*512);
  k_comb<<<8*544, 256, 0, stream>>>(dt_w, xp_w, xpcW);

  k_proj_ln<<<NTOK, 256, 0, stream>>>(x, proj_w, proj_b, p_ln_g, p_ln_b, h_res);

  for (int l = 0; l < NL; l++) {
    // LN -> bf16 (into act region; dead u_bf/g_bf space)
    k_ln_bf<<<NTOK/4, 256, 0, stream>>>(h_res, ln_g + l*DM, ln_b + l*DM, act);

    // in-proj: [8192x256] @ [1024x256]^T -> split upre (n<512) / zbuf (n>=512)
    {
      dim3 grid(NTOK/128, 1024/128);
      k_mfma<3><<<grid, 256, 0, stream>>>((const short*)act,
          (const short*)(inW + (size_t)l*1024*256), nullptr,
          upre, zbuf, 1024, 256, 256, 0);
    }

    // conv + silu -> u (f32) + u_bf (bf16, act region)
    k_conv_silu<<<(NTOK*DI)/256, 256, 0, stream>>>(upre, conv_w + l*DI*4,
                                                   conv_b + l*DI, u, act);

    // combined xp+dt proj: [8192x512] @ [544x512]^T -> dbl2 (dt softplus'ed)
    {
      dim3 grid(NTOK/128, 5);
      k_mfma<2><<<grid, 256, 0, stream>>>((const short*)act,
          (const short*)(xpcW + (size_t)l*544*512), dt_b + l*512,
          dbl2, nullptr, 544, 512, 512, 544);
    }

    // fused scan -> g_bf (act region)
    k_scan_f<<<B_*(DI/16), 256, 0, stream>>>(dbl2, u, zbuf,
        A_log + (size_t)l*DI*DS_, Dp + l*DI, act);

    // out-proj + residual: h += [8192x512] @ [256x512]^T
    {
      dim3 grid(NTOK/128, 2);
      k_mfma<1><<<grid, 256, 0, stream>>>((const short*)act,
          (const short*)(outW + (size_t)l*256*512), nullptr,
          h_res, nullptr, 256, 512, 512, 256);
    }
  }

  k_ln_bf<<<NTOK/4, 256, 0, stream>>>(h_res, pre_g, pre_b, act);
  k_pool<<<B_, 256, 0, stream>>>(act, lengths, pooled);
  k_head<<<B_, 128, 0, stream>>>(pooled, c1_w, c1_b, c2_w, c2_b, out);
}